// Round 1
// baseline (203.937 us; speedup 1.0000x reference)
//
#include <hip/hip_runtime.h>
#include <math.h>

#define F_CNT 1024
#define H_IMG 192
#define W_IMG 192
#define HW (H_IMG * W_IMG)
#define EPSF 1e-8f

// ws layout: F_CNT gaussians, sorted front-to-back, 12 floats each:
// [0]=mx [1]=my [2]=conA [3]=conB [4]=conC [5]=opac*valid [6]=r [7]=g [8]=b [9..11]=pad

__global__ __launch_bounds__(1024)
void prep_sort_kernel(const float* __restrict__ vp,
                      const int*   __restrict__ faces,
                      const float* __restrict__ rot_qs,
                      const float* __restrict__ log_scales,
                      const float* __restrict__ colors,
                      const float* __restrict__ log_opac,
                      float* __restrict__ params,
                      float* __restrict__ out)
{
    __shared__ float sp[9][F_CNT];
    __shared__ float skey[F_CNT];
    __shared__ int   sidx[F_CNT];

    const int f = threadIdx.x;
    if (f == 0) out[3 * HW] = 0.0f;   // zero the loss accumulator slot

    // ---- gather vertices ----
    const int ia = faces[3 * f + 0], ib = faces[3 * f + 1], ic = faces[3 * f + 2];
    const float Ax = vp[3 * ia + 0], Ay = vp[3 * ia + 1], Az = vp[3 * ia + 2];
    const float Bx = vp[3 * ib + 0], By = vp[3 * ib + 1], Bz = vp[3 * ib + 2];
    const float Cx = vp[3 * ic + 0], Cy = vp[3 * ic + 1], Cz = vp[3 * ic + 2];

    // ---- face coordinate frame ----
    const float tx = (Ax + Bx + Cx) / 3.0f;
    const float ty = (Ay + By + Cy) / 3.0f;
    const float tz = (Az + Bz + Cz) / 3.0f;

    const float e1x = Bx - Ax, e1y = By - Ay, e1z = Bz - Az;
    const float e2x = Cx - Ax, e2y = Cy - Ay, e2z = Cz - Az;

    const float n1 = sqrtf(e1x * e1x + e1y * e1y + e1z * e1z) + EPSF;
    const float ux = e1x / n1, uy = e1y / n1, uz = e1z / n1;   // x axis
    const float cnx = e1y * e2z - e1z * e2y;
    const float cny = e1z * e2x - e1x * e2z;
    const float cnz = e1x * e2y - e1y * e2x;
    const float n2 = sqrtf(cnx * cnx + cny * cny + cnz * cnz) + EPSF;
    const float wxv = cnx / n2, wyv = cny / n2, wzv = cnz / n2; // z axis
    const float vx = wyv * uz - wzv * uy;                       // y = cross(z, x)
    const float vy = wzv * ux - wxv * uz;
    const float vz = wxv * uy - wyv * ux;
    // faceR columns: col0 = (ux,uy,uz), col1 = (vx,vy,vz), col2 = (wxv,wyv,wzv)

    // ---- local gaussian rotation (quat_to_rot of gp_rot_qs) ----
    const float q0 = rot_qs[4 * f + 0], q1 = rot_qs[4 * f + 1];
    const float q2 = rot_qs[4 * f + 2], q3 = rot_qs[4 * f + 3];
    const float qn = sqrtf(q0 * q0 + q1 * q1 + q2 * q2 + q3 * q3) + EPSF;
    const float qw = q0 / qn, qx = q1 / qn, qy = q2 / qn, qz = q3 / qn;
    const float R00 = 1.0f - 2.0f * (qy * qy + qz * qz);
    const float R01 = 2.0f * (qx * qy - qw * qz);
    const float R02 = 2.0f * (qx * qz + qw * qy);
    const float R10 = 2.0f * (qx * qy + qw * qz);
    const float R11 = 1.0f - 2.0f * (qx * qx + qz * qz);
    const float R12 = 2.0f * (qy * qz - qw * qx);
    const float R20 = 2.0f * (qx * qz - qw * qy);
    const float R21 = 2.0f * (qy * qz + qw * qx);
    const float R22 = 1.0f - 2.0f * (qx * qx + qy * qy);

    const float s0 = expf(log_scales[3 * f + 0]);
    const float s1 = expf(log_scales[3 * f + 1]);
    const float s2 = expf(log_scales[3 * f + 2]);

    // gp_rs[k][j] = R[j][k] * s[k];  G = faceR @ gp_rs
    // G[i][j] = u_i*s0*R[j][0] + v_i*s1*R[j][1] + w_i*s2*R[j][2]
    float G00, G10, G20, G01, G11, G21, G02, G12, G22;
    {
        float c0 = s0 * R00, c1 = s1 * R01, c2 = s2 * R02;   // j = 0
        G00 = ux * c0 + vx * c1 + wxv * c2;
        G10 = uy * c0 + vy * c1 + wyv * c2;
        G20 = uz * c0 + vz * c1 + wzv * c2;
    }
    {
        float c0 = s0 * R10, c1 = s1 * R11, c2 = s2 * R12;   // j = 1
        G01 = ux * c0 + vx * c1 + wxv * c2;
        G11 = uy * c0 + vy * c1 + wyv * c2;
        G21 = uz * c0 + vz * c1 + wzv * c2;
    }
    {
        float c0 = s0 * R20, c1 = s1 * R21, c2 = s2 * R22;   // j = 2
        G02 = ux * c0 + vx * c1 + wxv * c2;
        G12 = uy * c0 + vy * c1 + wyv * c2;
        G22 = uz * c0 + vz * c1 + wzv * c2;
    }

    // column norms -> global scales; normalized columns -> global_rot
    const float gs0 = sqrtf(G00 * G00 + G10 * G10 + G20 * G20);
    const float gs1 = sqrtf(G01 * G01 + G11 * G11 + G21 * G21);
    const float gs2 = sqrtf(G02 * G02 + G12 * G12 + G22 * G22);
    const float d0 = gs0 + EPSF, d1 = gs1 + EPSF, d2 = gs2 + EPSF;
    const float r00 = G00 / d0, r10 = G10 / d0, r20 = G20 / d0;
    const float r01 = G01 / d1, r11 = G11 / d1, r21 = G21 / d1;
    const float r02 = G02 / d2, r12 = G12 / d2, r22 = G22 / d2;

    // rot_to_quat
    const float Qw = 0.5f * sqrtf(fmaxf(EPSF, 1.0f + r00 + r11 + r22));
    const float Qx = copysignf(0.5f * sqrtf(fmaxf(EPSF, 1.0f + r00 - r11 - r22)), r21 - r12);
    const float Qy = copysignf(0.5f * sqrtf(fmaxf(EPSF, 1.0f - r00 + r11 - r22)), r02 - r20);
    const float Qz = copysignf(0.5f * sqrtf(fmaxf(EPSF, 1.0f - r00 - r11 + r22)), r10 - r01);

    // render_gaussians: quat_to_rot(global_qs) (normalizes again)
    const float qn2 = sqrtf(Qw * Qw + Qx * Qx + Qy * Qy + Qz * Qz) + EPSF;
    const float pw = Qw / qn2, px = Qx / qn2, py = Qy / qn2, pz = Qz / qn2;
    const float N00 = 1.0f - 2.0f * (py * py + pz * pz);
    const float N01 = 2.0f * (px * py - pw * pz);
    const float N02 = 2.0f * (px * pz + pw * py);
    const float N10 = 2.0f * (px * py + pw * pz);
    const float N11 = 1.0f - 2.0f * (px * px + pz * pz);
    const float N12 = 2.0f * (py * pz - pw * px);
    const float N20 = 2.0f * (px * pz - pw * py);
    const float N21 = 2.0f * (py * pz + pw * px);
    const float N22 = 1.0f - 2.0f * (px * px + py * py);

    // M = N * diag(gs); cov3 = M M^T
    const float M00 = N00 * gs0, M01 = N01 * gs1, M02 = N02 * gs2;
    const float M10 = N10 * gs0, M11 = N11 * gs1, M12 = N12 * gs2;
    const float M20 = N20 * gs0, M21 = N21 * gs1, M22 = N22 * gs2;
    const float C00 = M00 * M00 + M01 * M01 + M02 * M02;
    const float C01 = M00 * M10 + M01 * M11 + M02 * M12;
    const float C02 = M00 * M20 + M01 * M21 + M02 * M22;
    const float C11 = M10 * M10 + M11 * M11 + M12 * M12;
    const float C12 = M10 * M20 + M11 * M21 + M12 * M22;
    const float C22 = M20 * M20 + M21 * M21 + M22 * M22;

    // projection
    const float valid = (tz > 0.2f) ? 1.0f : 0.0f;
    const float Zc = fmaxf(tz, 0.2f);
    const float mx = 200.0f * tx / Zc + 96.0f;
    const float my = 200.0f * ty / Zc + 96.0f;
    const float j00 = 200.0f / Zc;
    const float j02 = -200.0f * tx / (Zc * Zc);
    const float j11 = 200.0f / Zc;
    const float j12 = -200.0f * ty / (Zc * Zc);
    const float v00 = j00 * j00 * C00 + 2.0f * j00 * j02 * C02 + j02 * j02 * C22 + 0.3f;
    const float v01 = j00 * j11 * C01 + j00 * j12 * C02 + j02 * j11 * C12 + j02 * j12 * C22;
    const float v11 = j11 * j11 * C11 + 2.0f * j11 * j12 * C12 + j12 * j12 * C22 + 0.3f;
    const float det = fmaxf(v00 * v11 - v01 * v01, EPSF);
    const float conA = v11 / det, conB = -v01 / det, conC = v00 / det;
    const float opv = expf(log_opac[f]) * valid;

    sp[0][f] = mx;   sp[1][f] = my;
    sp[2][f] = conA; sp[3][f] = conB; sp[4][f] = conC;
    sp[5][f] = opv;
    sp[6][f] = colors[3 * f + 0];
    sp[7][f] = colors[3 * f + 1];
    sp[8][f] = colors[3 * f + 2];
    skey[f] = Zc;
    sidx[f] = f;

    // ---- bitonic sort on (Zc, idx): reproduces stable ascending argsort ----
    for (int k = 2; k <= F_CNT; k <<= 1) {
        for (int j = k >> 1; j > 0; j >>= 1) {
            __syncthreads();
            const int i = f;
            const int x = i ^ j;
            if (x > i) {
                float ki = skey[i], kx = skey[x];
                int   ii = sidx[i], ix = sidx[x];
                bool up = ((i & k) == 0);
                bool sw = up ? (ki > kx || (ki == kx && ii > ix))
                             : (ki < kx || (ki == kx && ii < ix));
                if (sw) {
                    skey[i] = kx; skey[x] = ki;
                    sidx[i] = ix; sidx[x] = ii;
                }
            }
        }
    }
    __syncthreads();

    // ---- write sorted AoS params (12 floats / gaussian) ----
    const int src = sidx[f];
    float* dst = params + 12 * f;
    #pragma unroll
    for (int k = 0; k < 9; ++k) dst[k] = sp[k][src];
    dst[9] = 0.0f; dst[10] = 0.0f; dst[11] = 0.0f;
}

__global__ __launch_bounds__(256)
void render_kernel(const float* __restrict__ params,
                   const float* __restrict__ img,
                   const float* __restrict__ mask,
                   float* __restrict__ out)
{
    const int tid = threadIdx.x;
    const int p = blockIdx.x * 256 + tid;
    const float fx = (float)(p % W_IMG);
    const float fy = (float)(p / W_IMG);

    float T = 1.0f, wsum = 0.0f, aR = 0.0f, aG = 0.0f, aB = 0.0f;
    const float4* __restrict__ P4 = (const float4*)params;

    #pragma unroll 4
    for (int i = 0; i < F_CNT; ++i) {
        // wave-uniform index -> scalar/broadcast loads
        const float4 p0 = P4[3 * i + 0];  // mx, my, conA, conB
        const float4 p1 = P4[3 * i + 1];  // conC, opv, r, g
        const float4 p2 = P4[3 * i + 2];  // b, pad...
        const float dx = fx - p0.x;
        const float dy = fy - p0.y;
        const float power = -0.5f * (p0.z * dx * dx + p1.x * dy * dy) - p0.w * dx * dy;
        const float alpha = fminf(fmaxf(p1.y * __expf(fminf(power, 0.0f)), 0.0f), 0.99f);
        const float wgt = alpha * T;
        aR += wgt * p1.z;
        aG += wgt * p1.w;
        aB += wgt * p2.x;
        wsum += wgt;
        T *= 1.0f - alpha;
    }

    const float bg = 1.0f - wsum;
    const float o0 = aR + bg, o1 = aG + bg, o2 = aB + bg;
    out[p]          = o0;
    out[HW + p]     = o1;
    out[2 * HW + p] = o2;

    // fused MSE loss vs masked image
    const float m = mask[p];
    const float base = 1.0f - m;
    const float e0 = o0 - (base + img[p] * m);
    const float e1 = o1 - (base + img[HW + p] * m);
    const float e2 = o2 - (base + img[2 * HW + p] * m);
    float s = e0 * e0 + e1 * e1 + e2 * e2;

    #pragma unroll
    for (int off = 32; off > 0; off >>= 1) s += __shfl_down(s, off);

    __shared__ float red[4];
    if ((tid & 63) == 0) red[tid >> 6] = s;
    __syncthreads();
    if (tid == 0) {
        atomicAdd(out + 3 * HW,
                  (red[0] + red[1] + red[2] + red[3]) * (1.0f / (float)(3 * HW)));
    }
}

extern "C" void kernel_launch(void* const* d_in, const int* in_sizes, int n_in,
                              void* d_out, int out_size, void* d_ws, size_t ws_size,
                              hipStream_t stream)
{
    const float* img        = (const float*)d_in[0];
    const float* mask       = (const float*)d_in[1];
    const float* vp         = (const float*)d_in[2];
    const int*   faces      = (const int*)d_in[3];
    const float* rot_qs     = (const float*)d_in[4];
    const float* log_scales = (const float*)d_in[5];
    const float* colors     = (const float*)d_in[6];
    const float* log_opac   = (const float*)d_in[7];
    float* out    = (float*)d_out;
    float* params = (float*)d_ws;   // 1024 * 12 floats = 48 KB

    prep_sort_kernel<<<1, F_CNT, 0, stream>>>(vp, faces, rot_qs, log_scales,
                                              colors, log_opac, params, out);
    render_kernel<<<HW / 256, 256, 0, stream>>>(params, img, mask, out);
}

// Round 5
// 129.535 us; speedup vs baseline: 1.5744x; 1.5744x over previous
//
#include <hip/hip_runtime.h>
#include <math.h>

#define F_CNT 1024
#define H_IMG 192
#define W_IMG 192
#define HW (H_IMG * W_IMG)
#define EPSF 1e-8f
#define N_SEG 8
#define SEG_LEN (F_CNT / N_SEG)     // 128
#define PIX_PER_BLK 64

// ws layout: F_CNT sorted gaussians, 12 floats each = 48 KB total (round-1-proven
// footprint; do NOT grow without knowing ws_size):
// [0]=mx [1]=my [2]=conA [3]=conB [4]=conC [5]=opac*valid [6]=r [7]=g [8]=b [9..11]=pad

// ---------------------------------------------------------------- kernel 1
// VERBATIM round-1 prep+sort (passed at absmax 3.9e-3): single block, LDS
// bitonic on (Zc, idx), gather-write sorted params to ws[0..48KB).
__global__ __launch_bounds__(1024)
void prep_sort_kernel(const float* __restrict__ vp,
                      const int*   __restrict__ faces,
                      const float* __restrict__ rot_qs,
                      const float* __restrict__ log_scales,
                      const float* __restrict__ colors,
                      const float* __restrict__ log_opac,
                      float* __restrict__ params,
                      float* __restrict__ out)
{
    __shared__ float sp[9][F_CNT];
    __shared__ float skey[F_CNT];
    __shared__ int   sidx[F_CNT];

    const int f = threadIdx.x;
    if (f == 0) out[3 * HW] = 0.0f;   // zero the loss accumulator slot

    // ---- gather vertices ----
    const int ia = faces[3 * f + 0], ib = faces[3 * f + 1], ic = faces[3 * f + 2];
    const float Ax = vp[3 * ia + 0], Ay = vp[3 * ia + 1], Az = vp[3 * ia + 2];
    const float Bx = vp[3 * ib + 0], By = vp[3 * ib + 1], Bz = vp[3 * ib + 2];
    const float Cx = vp[3 * ic + 0], Cy = vp[3 * ic + 1], Cz = vp[3 * ic + 2];

    // ---- face coordinate frame ----
    const float tx = (Ax + Bx + Cx) / 3.0f;
    const float ty = (Ay + By + Cy) / 3.0f;
    const float tz = (Az + Bz + Cz) / 3.0f;

    const float e1x = Bx - Ax, e1y = By - Ay, e1z = Bz - Az;
    const float e2x = Cx - Ax, e2y = Cy - Ay, e2z = Cz - Az;

    const float n1 = sqrtf(e1x * e1x + e1y * e1y + e1z * e1z) + EPSF;
    const float ux = e1x / n1, uy = e1y / n1, uz = e1z / n1;   // x axis
    const float cnx = e1y * e2z - e1z * e2y;
    const float cny = e1z * e2x - e1x * e2z;
    const float cnz = e1x * e2y - e1y * e2x;
    const float n2 = sqrtf(cnx * cnx + cny * cny + cnz * cnz) + EPSF;
    const float wxv = cnx / n2, wyv = cny / n2, wzv = cnz / n2; // z axis
    const float vx = wyv * uz - wzv * uy;                       // y = cross(z, x)
    const float vy = wzv * ux - wxv * uz;
    const float vz = wxv * uy - wyv * ux;

    // ---- local gaussian rotation (quat_to_rot of gp_rot_qs) ----
    const float q0 = rot_qs[4 * f + 0], q1 = rot_qs[4 * f + 1];
    const float q2 = rot_qs[4 * f + 2], q3 = rot_qs[4 * f + 3];
    const float qn = sqrtf(q0 * q0 + q1 * q1 + q2 * q2 + q3 * q3) + EPSF;
    const float qw = q0 / qn, qx = q1 / qn, qy = q2 / qn, qz = q3 / qn;
    const float R00 = 1.0f - 2.0f * (qy * qy + qz * qz);
    const float R01 = 2.0f * (qx * qy - qw * qz);
    const float R02 = 2.0f * (qx * qz + qw * qy);
    const float R10 = 2.0f * (qx * qy + qw * qz);
    const float R11 = 1.0f - 2.0f * (qx * qx + qz * qz);
    const float R12 = 2.0f * (qy * qz - qw * qx);
    const float R20 = 2.0f * (qx * qz - qw * qy);
    const float R21 = 2.0f * (qy * qz + qw * qx);
    const float R22 = 1.0f - 2.0f * (qx * qx + qy * qy);

    const float s0 = expf(log_scales[3 * f + 0]);
    const float s1 = expf(log_scales[3 * f + 1]);
    const float s2 = expf(log_scales[3 * f + 2]);

    // gp_rs[k][j] = R[j][k] * s[k];  G = faceR @ gp_rs
    float G00, G10, G20, G01, G11, G21, G02, G12, G22;
    {
        float c0 = s0 * R00, c1 = s1 * R01, c2 = s2 * R02;   // j = 0
        G00 = ux * c0 + vx * c1 + wxv * c2;
        G10 = uy * c0 + vy * c1 + wyv * c2;
        G20 = uz * c0 + vz * c1 + wzv * c2;
    }
    {
        float c0 = s0 * R10, c1 = s1 * R11, c2 = s2 * R12;   // j = 1
        G01 = ux * c0 + vx * c1 + wxv * c2;
        G11 = uy * c0 + vy * c1 + wyv * c2;
        G21 = uz * c0 + vz * c1 + wzv * c2;
    }
    {
        float c0 = s0 * R20, c1 = s1 * R21, c2 = s2 * R22;   // j = 2
        G02 = ux * c0 + vx * c1 + wxv * c2;
        G12 = uy * c0 + vy * c1 + wyv * c2;
        G22 = uz * c0 + vz * c1 + wzv * c2;
    }

    const float gs0 = sqrtf(G00 * G00 + G10 * G10 + G20 * G20);
    const float gs1 = sqrtf(G01 * G01 + G11 * G11 + G21 * G21);
    const float gs2 = sqrtf(G02 * G02 + G12 * G12 + G22 * G22);
    const float d0 = gs0 + EPSF, d1 = gs1 + EPSF, d2 = gs2 + EPSF;
    const float r00 = G00 / d0, r10 = G10 / d0, r20 = G20 / d0;
    const float r01 = G01 / d1, r11 = G11 / d1, r21 = G21 / d1;
    const float r02 = G02 / d2, r12 = G12 / d2, r22 = G22 / d2;

    // rot_to_quat
    const float Qw = 0.5f * sqrtf(fmaxf(EPSF, 1.0f + r00 + r11 + r22));
    const float Qx = copysignf(0.5f * sqrtf(fmaxf(EPSF, 1.0f + r00 - r11 - r22)), r21 - r12);
    const float Qy = copysignf(0.5f * sqrtf(fmaxf(EPSF, 1.0f - r00 + r11 - r22)), r02 - r20);
    const float Qz = copysignf(0.5f * sqrtf(fmaxf(EPSF, 1.0f - r00 - r11 + r22)), r10 - r01);

    // render_gaussians: quat_to_rot(global_qs) (normalizes again)
    const float qn2 = sqrtf(Qw * Qw + Qx * Qx + Qy * Qy + Qz * Qz) + EPSF;
    const float pw = Qw / qn2, px = Qx / qn2, py = Qy / qn2, pz = Qz / qn2;
    const float N00 = 1.0f - 2.0f * (py * py + pz * pz);
    const float N01 = 2.0f * (px * py - pw * pz);
    const float N02 = 2.0f * (px * pz + pw * py);
    const float N10 = 2.0f * (px * py + pw * pz);
    const float N11 = 1.0f - 2.0f * (px * px + pz * pz);
    const float N12 = 2.0f * (py * pz - pw * px);
    const float N20 = 2.0f * (px * pz - pw * py);
    const float N21 = 2.0f * (py * pz + pw * px);
    const float N22 = 1.0f - 2.0f * (px * px + py * py);

    // M = N * diag(gs); cov3 = M M^T
    const float M00 = N00 * gs0, M01 = N01 * gs1, M02 = N02 * gs2;
    const float M10 = N10 * gs0, M11 = N11 * gs1, M12 = N12 * gs2;
    const float M20 = N20 * gs0, M21 = N21 * gs1, M22 = N22 * gs2;
    const float C00 = M00 * M00 + M01 * M01 + M02 * M02;
    const float C01 = M00 * M10 + M01 * M11 + M02 * M12;
    const float C02 = M00 * M20 + M01 * M21 + M02 * M22;
    const float C11 = M10 * M10 + M11 * M11 + M12 * M12;
    const float C12 = M10 * M20 + M11 * M21 + M12 * M22;
    const float C22 = M20 * M20 + M21 * M21 + M22 * M22;

    // projection
    const float valid = (tz > 0.2f) ? 1.0f : 0.0f;
    const float Zc = fmaxf(tz, 0.2f);
    const float mx = 200.0f * tx / Zc + 96.0f;
    const float my = 200.0f * ty / Zc + 96.0f;
    const float j00 = 200.0f / Zc;
    const float j02 = -200.0f * tx / (Zc * Zc);
    const float j11 = 200.0f / Zc;
    const float j12 = -200.0f * ty / (Zc * Zc);
    const float v00 = j00 * j00 * C00 + 2.0f * j00 * j02 * C02 + j02 * j02 * C22 + 0.3f;
    const float v01 = j00 * j11 * C01 + j00 * j12 * C02 + j02 * j11 * C12 + j02 * j12 * C22;
    const float v11 = j11 * j11 * C11 + 2.0f * j11 * j12 * C12 + j12 * j12 * C22 + 0.3f;
    const float det = fmaxf(v00 * v11 - v01 * v01, EPSF);
    const float conA = v11 / det, conB = -v01 / det, conC = v00 / det;
    const float opv = expf(log_opac[f]) * valid;

    sp[0][f] = mx;   sp[1][f] = my;
    sp[2][f] = conA; sp[3][f] = conB; sp[4][f] = conC;
    sp[5][f] = opv;
    sp[6][f] = colors[3 * f + 0];
    sp[7][f] = colors[3 * f + 1];
    sp[8][f] = colors[3 * f + 2];
    skey[f] = Zc;
    sidx[f] = f;

    // ---- bitonic sort on (Zc, idx): reproduces stable ascending argsort ----
    for (int k = 2; k <= F_CNT; k <<= 1) {
        for (int j = k >> 1; j > 0; j >>= 1) {
            __syncthreads();
            const int i = f;
            const int x = i ^ j;
            if (x > i) {
                float ki = skey[i], kx = skey[x];
                int   ii = sidx[i], ix = sidx[x];
                bool up = ((i & k) == 0);
                bool sw = up ? (ki > kx || (ki == kx && ii > ix))
                             : (ki < kx || (ki == kx && ii < ix));
                if (sw) {
                    skey[i] = kx; skey[x] = ki;
                    sidx[i] = ix; sidx[x] = ii;
                }
            }
        }
    }
    __syncthreads();

    // ---- write sorted AoS params (12 floats / gaussian) ----
    const int src = sidx[f];
    float* dst = params + 12 * f;
    #pragma unroll
    for (int k = 0; k < 9; ++k) dst[k] = sp[k][src];
    dst[9] = 0.0f; dst[10] = 0.0f; dst[11] = 0.0f;
}

// ---------------------------------------------------------------- kernel 2
// fused render: 64 pixels x 8 depth-segments per block (512 threads).
// wave w composites segment w (128 gaussians staged in its own LDS slice),
// then lanes of wave 0 fold the 8 (C, T, wsum) partials front-to-back.
// bg = 1 - total wsum (round-1's numeric path).
__global__ __launch_bounds__(512)
void render_kernel(const float* __restrict__ params,
                   const float* __restrict__ img,
                   const float* __restrict__ mask,
                   float* __restrict__ out)
{
    __shared__ float4 lds4[N_SEG * SEG_LEN * 3];   // 48 KB
    __shared__ float  sw[N_SEG][PIX_PER_BLK];      // 2 KB
    const int tid  = threadIdx.x;
    const int lane = tid & 63;
    const int seg  = tid >> 6;

    // stage this wave's segment (6 KB) — same-wave write->read, in-order LDS pipe
    const float4* __restrict__ g4 = (const float4*)params + seg * (SEG_LEN * 3);
    float4* __restrict__ L4 = lds4 + seg * (SEG_LEN * 3);
    #pragma unroll
    for (int k = 0; k < 6; ++k)
        L4[k * 64 + lane] = g4[k * 64 + lane];

    const int p = blockIdx.x * PIX_PER_BLK + lane;
    const float fx = (float)(p % W_IMG);
    const float fy = (float)(p / W_IMG);

    float T = 1.0f, wsum = 0.0f, aR = 0.0f, aG = 0.0f, aB = 0.0f;
    #pragma unroll 4
    for (int i = 0; i < SEG_LEN; ++i) {
        const float4 p0 = L4[3 * i + 0];  // mx, my, conA, conB (LDS broadcast)
        const float4 p1 = L4[3 * i + 1];  // conC, opv, r, g
        const float4 p2 = L4[3 * i + 2];  // b, pad
        const float dx = fx - p0.x;
        const float dy = fy - p0.y;
        const float power = -0.5f * (p0.z * dx * dx + p1.x * dy * dy) - p0.w * dx * dy;
        const float alpha = fminf(fmaxf(p1.y * __expf(fminf(power, 0.0f)), 0.0f), 0.99f);
        const float wgt = alpha * T;
        aR += wgt * p1.z;
        aG += wgt * p1.w;
        aB += wgt * p2.x;
        wsum += wgt;
        T *= 1.0f - alpha;
    }

    __syncthreads();                       // all waves done reading params
    lds4[seg * 64 + lane] = make_float4(aR, aG, aB, T);   // reuse LDS for partials
    sw[seg][lane] = wsum;
    __syncthreads();

    if (tid < 64) {
        float R = 0.0f, G = 0.0f, B = 0.0f, Tt = 1.0f, W = 0.0f;
        #pragma unroll
        for (int s = 0; s < N_SEG; ++s) {
            const float4 c = lds4[s * 64 + tid];
            R += Tt * c.x; G += Tt * c.y; B += Tt * c.z;
            W += Tt * sw[s][tid];
            Tt *= c.w;
        }
        const float bg = 1.0f - W;          // round-1 background path
        const float o0 = R + bg, o1 = G + bg, o2 = B + bg;
        out[p]          = o0;
        out[HW + p]     = o1;
        out[2 * HW + p] = o2;

        const float m = mask[p];
        const float base = 1.0f - m;
        const float e0 = o0 - (base + img[p] * m);
        const float e1 = o1 - (base + img[HW + p] * m);
        const float e2 = o2 - (base + img[2 * HW + p] * m);
        float s = e0 * e0 + e1 * e1 + e2 * e2;

        #pragma unroll
        for (int off = 32; off > 0; off >>= 1) s += __shfl_down(s, off);
        if (tid == 0)
            atomicAdd(out + 3 * HW, s * (1.0f / (float)(3 * HW)));
    }
}

extern "C" void kernel_launch(void* const* d_in, const int* in_sizes, int n_in,
                              void* d_out, int out_size, void* d_ws, size_t ws_size,
                              hipStream_t stream)
{
    const float* img        = (const float*)d_in[0];
    const float* mask       = (const float*)d_in[1];
    const float* vp         = (const float*)d_in[2];
    const int*   faces      = (const int*)d_in[3];
    const float* rot_qs     = (const float*)d_in[4];
    const float* log_scales = (const float*)d_in[5];
    const float* colors     = (const float*)d_in[6];
    const float* log_opac   = (const float*)d_in[7];
    float* out    = (float*)d_out;
    float* params = (float*)d_ws;   // 48 KB — round-1-proven footprint

    prep_sort_kernel<<<1, F_CNT, 0, stream>>>(vp, faces, rot_qs, log_scales,
                                              colors, log_opac, params, out);
    render_kernel<<<HW / PIX_PER_BLK, 512, 0, stream>>>(params, img, mask, out);
}

// Round 8
// 126.312 us; speedup vs baseline: 1.6146x; 1.0255x over previous
//
#include <hip/hip_runtime.h>
#include <hip/hip_fp16.h>
#include <math.h>

#define F_CNT 1024
#define H_IMG 192
#define W_IMG 192
#define HW (H_IMG * W_IMG)
#define EPSF 1e-8f
#define N_SEG 8
#define SEG_LEN 128
#define PIX_PER_BLK 144          // 256 blocks x 144 px = 36864 exactly
#define LOG2E 1.4426950408889634f

// ws layout: F_CNT sorted records, 8 floats (32 B) each = 32 KB total
// (under the proven-safe 48 KB footprint):
//   [mx, my, LA, LB, LC, opv, h2(r,g), h2(b,0)]
//   LA = 0.5*log2e*conA, LB = log2e*conB, LC = 0.5*log2e*conC
// so alpha = min(opv * exp2(-(LA*dx^2 + LB*dx*dy + LC*dy^2)), 0.99).

// ---------------------------------------------------------------- kernel 1
// Proven single-block prep+sort (R1/R5 structure, verbatim math):
// per-face math -> LDS rows -> bitonic (Zc, idx) -> gather-write records.
__global__ __launch_bounds__(1024)
void prep_sort_kernel(const float* __restrict__ vp,
                      const int*   __restrict__ faces,
                      const float* __restrict__ rot_qs,
                      const float* __restrict__ log_scales,
                      const float* __restrict__ colors,
                      const float* __restrict__ log_opac,
                      float* __restrict__ params,
                      float* __restrict__ out)
{
    __shared__ float sp[8][F_CNT];
    __shared__ float skey[F_CNT];
    __shared__ int   sidx[F_CNT];

    const int f = threadIdx.x;
    if (f == 0) out[3 * HW] = 0.0f;   // zero the loss accumulator slot

    // ---- gather vertices ----
    const int ia = faces[3 * f + 0], ib = faces[3 * f + 1], ic = faces[3 * f + 2];
    const float Ax = vp[3 * ia + 0], Ay = vp[3 * ia + 1], Az = vp[3 * ia + 2];
    const float Bx = vp[3 * ib + 0], By = vp[3 * ib + 1], Bz = vp[3 * ib + 2];
    const float Cx = vp[3 * ic + 0], Cy = vp[3 * ic + 1], Cz = vp[3 * ic + 2];

    // ---- face coordinate frame ----
    const float tx = (Ax + Bx + Cx) / 3.0f;
    const float ty = (Ay + By + Cy) / 3.0f;
    const float tz = (Az + Bz + Cz) / 3.0f;

    const float e1x = Bx - Ax, e1y = By - Ay, e1z = Bz - Az;
    const float e2x = Cx - Ax, e2y = Cy - Ay, e2z = Cz - Az;

    const float n1 = sqrtf(e1x * e1x + e1y * e1y + e1z * e1z) + EPSF;
    const float ux = e1x / n1, uy = e1y / n1, uz = e1z / n1;   // x axis
    const float cnx = e1y * e2z - e1z * e2y;
    const float cny = e1z * e2x - e1x * e2z;
    const float cnz = e1x * e2y - e1y * e2x;
    const float n2 = sqrtf(cnx * cnx + cny * cny + cnz * cnz) + EPSF;
    const float wxv = cnx / n2, wyv = cny / n2, wzv = cnz / n2; // z axis
    const float vx = wyv * uz - wzv * uy;                       // y = cross(z, x)
    const float vy = wzv * ux - wxv * uz;
    const float vz = wxv * uy - wyv * ux;

    // ---- local gaussian rotation (quat_to_rot of gp_rot_qs) ----
    const float q0 = rot_qs[4 * f + 0], q1 = rot_qs[4 * f + 1];
    const float q2 = rot_qs[4 * f + 2], q3 = rot_qs[4 * f + 3];
    const float qn = sqrtf(q0 * q0 + q1 * q1 + q2 * q2 + q3 * q3) + EPSF;
    const float qw = q0 / qn, qx = q1 / qn, qy = q2 / qn, qz = q3 / qn;
    const float R00 = 1.0f - 2.0f * (qy * qy + qz * qz);
    const float R01 = 2.0f * (qx * qy - qw * qz);
    const float R02 = 2.0f * (qx * qz + qw * qy);
    const float R10 = 2.0f * (qx * qy + qw * qz);
    const float R11 = 1.0f - 2.0f * (qx * qx + qz * qz);
    const float R12 = 2.0f * (qy * qz - qw * qx);
    const float R20 = 2.0f * (qx * qz - qw * qy);
    const float R21 = 2.0f * (qy * qz + qw * qx);
    const float R22 = 1.0f - 2.0f * (qx * qx + qy * qy);

    const float s0 = expf(log_scales[3 * f + 0]);
    const float s1 = expf(log_scales[3 * f + 1]);
    const float s2 = expf(log_scales[3 * f + 2]);

    // gp_rs[k][j] = R[j][k] * s[k];  G = faceR @ gp_rs
    float G00, G10, G20, G01, G11, G21, G02, G12, G22;
    {
        float c0 = s0 * R00, c1 = s1 * R01, c2 = s2 * R02;   // j = 0
        G00 = ux * c0 + vx * c1 + wxv * c2;
        G10 = uy * c0 + vy * c1 + wyv * c2;
        G20 = uz * c0 + vz * c1 + wzv * c2;
    }
    {
        float c0 = s0 * R10, c1 = s1 * R11, c2 = s2 * R12;   // j = 1
        G01 = ux * c0 + vx * c1 + wxv * c2;
        G11 = uy * c0 + vy * c1 + wyv * c2;
        G21 = uz * c0 + vz * c1 + wzv * c2;
    }
    {
        float c0 = s0 * R20, c1 = s1 * R21, c2 = s2 * R22;   // j = 2
        G02 = ux * c0 + vx * c1 + wxv * c2;
        G12 = uy * c0 + vy * c1 + wyv * c2;
        G22 = uz * c0 + vz * c1 + wzv * c2;
    }

    const float gs0 = sqrtf(G00 * G00 + G10 * G10 + G20 * G20);
    const float gs1 = sqrtf(G01 * G01 + G11 * G11 + G21 * G21);
    const float gs2 = sqrtf(G02 * G02 + G12 * G12 + G22 * G22);
    const float d0 = gs0 + EPSF, d1 = gs1 + EPSF, d2 = gs2 + EPSF;
    const float r00 = G00 / d0, r10 = G10 / d0, r20 = G20 / d0;
    const float r01 = G01 / d1, r11 = G11 / d1, r21 = G21 / d1;
    const float r02 = G02 / d2, r12 = G12 / d2, r22 = G22 / d2;

    // rot_to_quat
    const float Qw = 0.5f * sqrtf(fmaxf(EPSF, 1.0f + r00 + r11 + r22));
    const float Qx = copysignf(0.5f * sqrtf(fmaxf(EPSF, 1.0f + r00 - r11 - r22)), r21 - r12);
    const float Qy = copysignf(0.5f * sqrtf(fmaxf(EPSF, 1.0f - r00 + r11 - r22)), r02 - r20);
    const float Qz = copysignf(0.5f * sqrtf(fmaxf(EPSF, 1.0f - r00 - r11 + r22)), r10 - r01);

    // render_gaussians: quat_to_rot(global_qs) (normalizes again)
    const float qn2 = sqrtf(Qw * Qw + Qx * Qx + Qy * Qy + Qz * Qz) + EPSF;
    const float pw = Qw / qn2, px = Qx / qn2, py = Qy / qn2, pz = Qz / qn2;
    const float N00 = 1.0f - 2.0f * (py * py + pz * pz);
    const float N01 = 2.0f * (px * py - pw * pz);
    const float N02 = 2.0f * (px * pz + pw * py);
    const float N10 = 2.0f * (px * py + pw * pz);
    const float N11 = 1.0f - 2.0f * (px * px + pz * pz);
    const float N12 = 2.0f * (py * pz - pw * px);
    const float N20 = 2.0f * (px * pz - pw * py);
    const float N21 = 2.0f * (py * pz + pw * px);
    const float N22 = 1.0f - 2.0f * (px * px + py * py);

    // M = N * diag(gs); cov3 = M M^T
    const float M00 = N00 * gs0, M01 = N01 * gs1, M02 = N02 * gs2;
    const float M10 = N10 * gs0, M11 = N11 * gs1, M12 = N12 * gs2;
    const float M20 = N20 * gs0, M21 = N21 * gs1, M22 = N22 * gs2;
    const float C00 = M00 * M00 + M01 * M01 + M02 * M02;
    const float C01 = M00 * M10 + M01 * M11 + M02 * M12;
    const float C02 = M00 * M20 + M01 * M21 + M02 * M22;
    const float C11 = M10 * M10 + M11 * M11 + M12 * M12;
    const float C12 = M10 * M20 + M11 * M21 + M12 * M22;
    const float C22 = M20 * M20 + M21 * M21 + M22 * M22;

    // projection
    const float valid = (tz > 0.2f) ? 1.0f : 0.0f;
    const float Zc = fmaxf(tz, 0.2f);
    const float mx = 200.0f * tx / Zc + 96.0f;
    const float my = 200.0f * ty / Zc + 96.0f;
    const float j00 = 200.0f / Zc;
    const float j02 = -200.0f * tx / (Zc * Zc);
    const float j11 = 200.0f / Zc;
    const float j12 = -200.0f * ty / (Zc * Zc);
    const float v00 = j00 * j00 * C00 + 2.0f * j00 * j02 * C02 + j02 * j02 * C22 + 0.3f;
    const float v01 = j00 * j11 * C01 + j00 * j12 * C02 + j02 * j11 * C12 + j02 * j12 * C22;
    const float v11 = j11 * j11 * C11 + 2.0f * j11 * j12 * C12 + j12 * j12 * C22 + 0.3f;
    const float det = fmaxf(v00 * v11 - v01 * v01, EPSF);
    const float conA = v11 / det, conB = -v01 / det, conC = v00 / det;
    const float opv = expf(log_opac[f]) * valid;

    union { __half2 h; float f; } c01u, c2u;
    c01u.h = __floats2half2_rn(colors[3 * f + 0], colors[3 * f + 1]);
    c2u.h  = __floats2half2_rn(colors[3 * f + 2], 0.0f);

    sp[0][f] = mx;
    sp[1][f] = my;
    sp[2][f] = 0.5f * LOG2E * conA;   // LA
    sp[3][f] = LOG2E * conB;          // LB
    sp[4][f] = 0.5f * LOG2E * conC;   // LC
    sp[5][f] = opv;
    sp[6][f] = c01u.f;
    sp[7][f] = c2u.f;
    skey[f] = Zc;
    sidx[f] = f;

    // ---- bitonic sort on (Zc, idx): reproduces stable ascending argsort ----
    for (int k = 2; k <= F_CNT; k <<= 1) {
        for (int j = k >> 1; j > 0; j >>= 1) {
            __syncthreads();
            const int i = f;
            const int x = i ^ j;
            if (x > i) {
                float ki = skey[i], kx = skey[x];
                int   ii = sidx[i], ix = sidx[x];
                bool up = ((i & k) == 0);
                bool sw = up ? (ki > kx || (ki == kx && ii > ix))
                             : (ki < kx || (ki == kx && ii < ix));
                if (sw) {
                    skey[i] = kx; skey[x] = ki;
                    sidx[i] = ix; sidx[x] = ii;
                }
            }
        }
    }
    __syncthreads();

    // ---- gather-write sorted 32 B records ----
    const int src = sidx[f];
    float4* __restrict__ d4 = (float4*)params + 2 * f;
    d4[0] = make_float4(sp[0][src], sp[1][src], sp[2][src], sp[3][src]);
    d4[1] = make_float4(sp[4][src], sp[5][src], sp[6][src], sp[7][src]);
}

// ---------------------------------------------------------------- kernel 2
// 256 blocks x 144 px (exact CU balance). 512 threads = 8 waves; wave w
// composites depth-segment w (128 sorted records in LDS, broadcast reads);
// each lane covers px slots {lane, lane+64, lane<16: lane+128}. The 8
// (C, T) partials fold front-to-back; bg telescopes to T_total.
__global__ __launch_bounds__(512)
void render_kernel(const float* __restrict__ params,
                   const float* __restrict__ img,
                   const float* __restrict__ mask,
                   float* __restrict__ out)
{
    __shared__ float4 lds4[F_CNT * 2];   // 32 KB; reused for fold partials
    const int tid  = threadIdx.x;
    const int lane = tid & 63;
    const int wv   = tid >> 6;

    // ---- stage all 1024 sorted records: contiguous, coalesced ----
    const float4* __restrict__ rec4 = (const float4*)params;
    #pragma unroll
    for (int k = 0; k < 4; ++k)
        lds4[k * 512 + tid] = rec4[k * 512 + tid];
    __syncthreads();

    const int pbase = blockIdx.x * PIX_PER_BLK;
    const int p0 = pbase + lane, p1 = p0 + 64, p2 = p0 + 128;
    const float fx0 = (float)(p0 % W_IMG), fy0 = (float)(p0 / W_IMG);
    const float fx1 = (float)(p1 % W_IMG), fy1 = (float)(p1 / W_IMG);
    const float fx2 = (float)(p2 % W_IMG), fy2 = (float)(p2 / W_IMG);

    float T0 = 1.0f, R0 = 0.0f, G0 = 0.0f, B0 = 0.0f;
    float T1 = 1.0f, R1 = 0.0f, G1 = 0.0f, B1 = 0.0f;
    float T2 = 1.0f, R2 = 0.0f, G2 = 0.0f, B2 = 0.0f;

    const float4* __restrict__ Lb = lds4 + (wv << 8);   // wv*128 records * 2
    #pragma unroll 4
    for (int i = 0; i < SEG_LEN; ++i) {
        const float4 a = Lb[2 * i + 0];   // mx, my, LA, LB (broadcast)
        const float4 b = Lb[2 * i + 1];   // LC, opv, h2(r,g), h2(b,0)
        union { float f; __half2 h; } urg, ub;
        urg.f = b.z;  ub.f = b.w;
        const float2 crg = __half22float2(urg.h);
        const float  cb  = __low2float(ub.h);

        {   // slot 0
            const float dx = fx0 - a.x, dy = fy0 - a.y;
            const float t  = fmaf(a.w, dy, a.z * dx);
            const float u2 = (b.x * dy) * dy;
            const float n  = -fmaf(t, dx, u2);
            const float e  = exp2f(fminf(n, 0.0f));
            const float al = fminf(b.y * e, 0.99f);
            const float w  = al * T0;
            R0 = fmaf(w, crg.x, R0); G0 = fmaf(w, crg.y, G0); B0 = fmaf(w, cb, B0);
            T0 -= w;
        }
        {   // slot 1
            const float dx = fx1 - a.x, dy = fy1 - a.y;
            const float t  = fmaf(a.w, dy, a.z * dx);
            const float u2 = (b.x * dy) * dy;
            const float n  = -fmaf(t, dx, u2);
            const float e  = exp2f(fminf(n, 0.0f));
            const float al = fminf(b.y * e, 0.99f);
            const float w  = al * T1;
            R1 = fmaf(w, crg.x, R1); G1 = fmaf(w, crg.y, G1); B1 = fmaf(w, cb, B1);
            T1 -= w;
        }
        {   // slot 2 (only lanes < 16 are real pixels; extra math is harmless)
            const float dx = fx2 - a.x, dy = fy2 - a.y;
            const float t  = fmaf(a.w, dy, a.z * dx);
            const float u2 = (b.x * dy) * dy;
            const float n  = -fmaf(t, dx, u2);
            const float e  = exp2f(fminf(n, 0.0f));
            const float al = fminf(b.y * e, 0.99f);
            const float w  = al * T2;
            R2 = fmaf(w, crg.x, R2); G2 = fmaf(w, crg.y, G2); B2 = fmaf(w, cb, B2);
            T2 -= w;
        }
    }

    __syncthreads();                       // all waves done reading records
    float4* __restrict__ fold4 = lds4;     // [8][144] partials
    fold4[wv * PIX_PER_BLK + lane]      = make_float4(R0, G0, B0, T0);
    fold4[wv * PIX_PER_BLK + 64 + lane] = make_float4(R1, G1, B1, T1);
    if (lane < 16)
        fold4[wv * PIX_PER_BLK + 128 + lane] = make_float4(R2, G2, B2, T2);
    __syncthreads();

    float lsum = 0.0f;
    if (tid < PIX_PER_BLK) {
        float R = 0.0f, G = 0.0f, B = 0.0f, Tt = 1.0f;
        #pragma unroll
        for (int s = 0; s < N_SEG; ++s) {
            const float4 c = fold4[s * PIX_PER_BLK + tid];
            R += Tt * c.x; G += Tt * c.y; B += Tt * c.z;
            Tt *= c.w;
        }
        const float bg = Tt;               // sum(w) telescopes to 1 - T_total
        const float o0 = R + bg, o1 = G + bg, o2 = B + bg;
        const int p = pbase + tid;
        out[p]          = o0;
        out[HW + p]     = o1;
        out[2 * HW + p] = o2;

        const float m = mask[p];
        const float base = 1.0f - m;
        const float e0 = o0 - (base + img[p] * m);
        const float e1 = o1 - (base + img[HW + p] * m);
        const float e2 = o2 - (base + img[2 * HW + p] * m);
        lsum = e0 * e0 + e1 * e1 + e2 * e2;
    }

    float* __restrict__ lossb = (float*)lds4 + (N_SEG * PIX_PER_BLK * 4);
    if (tid < PIX_PER_BLK) lossb[tid] = lsum;
    __syncthreads();
    if (tid < 64) {
        float s = lossb[tid] + lossb[tid + 64] + (tid < 16 ? lossb[tid + 128] : 0.0f);
        #pragma unroll
        for (int off = 32; off > 0; off >>= 1) s += __shfl_down(s, off);
        if (tid == 0)
            atomicAdd(out + 3 * HW, s * (1.0f / (float)(3 * HW)));
    }
}

extern "C" void kernel_launch(void* const* d_in, const int* in_sizes, int n_in,
                              void* d_out, int out_size, void* d_ws, size_t ws_size,
                              hipStream_t stream)
{
    const float* img        = (const float*)d_in[0];
    const float* mask       = (const float*)d_in[1];
    const float* vp         = (const float*)d_in[2];
    const int*   faces      = (const int*)d_in[3];
    const float* rot_qs     = (const float*)d_in[4];
    const float* log_scales = (const float*)d_in[5];
    const float* colors     = (const float*)d_in[6];
    const float* log_opac   = (const float*)d_in[7];
    float* out    = (float*)d_out;
    float* params = (float*)d_ws;   // 32 KB used (<= proven 48 KB)

    prep_sort_kernel<<<1, F_CNT, 0, stream>>>(vp, faces, rot_qs, log_scales,
                                              colors, log_opac, params, out);
    render_kernel<<<HW / PIX_PER_BLK, 512, 0, stream>>>(params, img, mask, out);
}